// Round 19
// baseline (447.943 us; speedup 1.0000x reference)
//
#include <hip/hip_runtime.h>

typedef __attribute__((ext_vector_type(8))) short short8;
typedef __attribute__((ext_vector_type(4))) float f32x4;
typedef __attribute__((ext_vector_type(2))) unsigned u32x2;

#define NN 4096
#define BN_EPS 1e-3f

__device__ inline unsigned short f2bf(float f) {
    unsigned u = __builtin_bit_cast(unsigned, f);
    return (unsigned short)((u + 0x7fffu + ((u >> 16) & 1u)) >> 16);
}
__device__ inline float bf2f(unsigned short h) {
    return __builtin_bit_cast(float, ((unsigned)h) << 16);
}

// ---------------------------------------------------------------------------
// LDS-staged MFMA gcn. adj staged via LDS so global reads are 1 KB
// single-segment bursts (one adj row per instruction); MFMA B-fragments
// come from LDS. R17/R18 bug fixed: the A-fragment global load must also
// carry the grp*8 k-slot offset (lane group grp holds k-elements
// grp*8..grp*8+7 of each 32-k MFMA window) — it was dropped when the B
// side moved to LDS, pairing mismatched k-slots (deterministic 2.3e-2).
// Block: 256 thr = 4 waves on the same 16 output rows, 4-way K-split.
// Fused LDS-reduce + bias/ReLU/BN epilogue.
// ---------------------------------------------------------------------------
__global__ __launch_bounds__(256) void m72c_gcn(
    const float* __restrict__ adj, const unsigned short* __restrict__ tT,
    const float* __restrict__ bias, const float* __restrict__ gamma,
    const float* __restrict__ beta, const float* __restrict__ mean,
    const float* __restrict__ var, unsigned short* __restrict__ xout)
{
    __shared__ unsigned short Ast[4][16][264];   // [wave][row][m'] bf16, pad 8
    __shared__ float red[4][16][68];
    const int tid = threadIdx.x;
    const int s = tid >> 6, lane = tid & 63;
    const int rl = lane & 15, grp = lane >> 4;
    const int bid = blockIdx.x;
    const int b = bid >> 8, rb = bid & 255;
    const int row16 = rb * 16;

    const float* abase = adj + ((long)b * NN + row16) * (long)NN;
    const unsigned short* t0 = tT + ((long)b * 64 + rl) * (long)NN;
    const unsigned short* t1 = t0 + 16 * (long)NN;
    const unsigned short* t2 = t0 + 32 * (long)NN;
    const unsigned short* t3 = t0 + 48 * (long)NN;
    const int m0 = s * 1024;

    f32x4 a0 = {}, a1 = {}, a2 = {}, a3 = {};

    for (int sc = 0; sc < 4; ++sc) {
        const int mb = m0 + sc * 256;
        // ---- stage: 16 rows x 256 fp32 -> bf16 LDS; 1 KB burst per instr ----
#pragma unroll
        for (int r = 0; r < 16; ++r) {
            f32x4 v = *(const f32x4*)(abase + (long)r * NN + mb + lane * 4);
            u32x2 p;
            p.x = (unsigned)f2bf(v.x) | ((unsigned)f2bf(v.y) << 16);
            p.y = (unsigned)f2bf(v.z) | ((unsigned)f2bf(v.w) << 16);
            *(u32x2*)&Ast[s][r][lane * 4] = p;
        }
        __syncthreads();   // ds_write -> ds_read ordering
        // ---- consume: 8 MFMA steps over the 256-col sub-chunk ----
#pragma unroll
        for (int it = 0; it < 8; ++it) {
            const int kk = it * 32 + grp * 8;      // k-slot offset incl. grp
            const int mA = mb + kk;
            short8 A0 = *(const short8*)(t0 + mA);
            short8 A1 = *(const short8*)(t1 + mA);
            short8 A2 = *(const short8*)(t2 + mA);
            short8 A3 = *(const short8*)(t3 + mA);
            short8 B = *(const short8*)&Ast[s][rl][kk];
            a0 = __builtin_amdgcn_mfma_f32_16x16x32_bf16(A0, B, a0, 0, 0, 0);
            a1 = __builtin_amdgcn_mfma_f32_16x16x32_bf16(A1, B, a1, 0, 0, 0);
            a2 = __builtin_amdgcn_mfma_f32_16x16x32_bf16(A2, B, a2, 0, 0, 0);
            a3 = __builtin_amdgcn_mfma_f32_16x16x32_bf16(A3, B, a3, 0, 0, 0);
        }
        __syncthreads();   // ds_read -> next chunk's ds_write ordering
    }

    // D layout: col=rl -> node; row=grp*4+q -> feature within 16-group.
    *(f32x4*)&red[s][rl][ 0 + grp * 4] = a0;
    *(f32x4*)&red[s][rl][16 + grp * 4] = a1;
    *(f32x4*)&red[s][rl][32 + grp * 4] = a2;
    *(f32x4*)&red[s][rl][48 + grp * 4] = a3;
    __syncthreads();

    const int r2 = tid >> 4, cq = (tid & 15) * 4;
    f32x4 v = *(const f32x4*)&red[0][r2][cq];
    v += *(const f32x4*)&red[1][r2][cq];
    v += *(const f32x4*)&red[2][r2][cq];
    v += *(const f32x4*)&red[3][r2][cq];

    f32x4 bi = *(const f32x4*)(bias + cq);
    f32x4 mn = *(const f32x4*)(mean + cq);
    f32x4 vr = *(const f32x4*)(var + cq);
    f32x4 gm = *(const f32x4*)(gamma + cq);
    f32x4 bt = *(const f32x4*)(beta + cq);
    float o[4];
    for (int q = 0; q < 4; ++q) {
        float h = v[q] + bi[q];
        h = h > 0.f ? h : 0.f;
        o[q] = (h - mn[q]) * (gm[q] / sqrtf(vr[q] + BN_EPS)) + bt[q];
    }
    u32x2 o2;
    o2.x = (unsigned)f2bf(o[0]) | ((unsigned)f2bf(o[1]) << 16);
    o2.y = (unsigned)f2bf(o[2]) | ((unsigned)f2bf(o[3]) << 16);
    *(u32x2*)(xout + ((long)b * NN + row16 + r2) * 64 + cq) = o2;
}

// ---------------------------------------------------------------------------
// Feature transform: tT[b][c][n] = sum_k xin[b][n][k] * W[k][c]  (bf16 out)
// ---------------------------------------------------------------------------
__global__ __launch_bounds__(256) void h72_feat32(
    const float* __restrict__ xin, const float* __restrict__ W,
    unsigned short* __restrict__ tT)
{
    __shared__ float xs[64][68];
    __shared__ float Ws[64][68];
    const int tid = threadIdx.x;
    const int bid = blockIdx.x;
    const int b = bid >> 6, nb = bid & 63;
    {
        const int rr = tid >> 2, kq = (tid & 3) * 16;
        const float* xp = xin + ((long)b * NN + nb * 64 + rr) * 64 + kq;
        const float* wp = W + rr * 64 + kq;
        for (int j = 0; j < 4; ++j) {
            *(f32x4*)&xs[rr][kq + j * 4] = *(const f32x4*)(xp + j * 4);
            *(f32x4*)&Ws[rr][kq + j * 4] = *(const f32x4*)(wp + j * 4);
        }
    }
    __syncthreads();
    const int c = tid >> 2, n0 = (tid & 3) * 16;
    float outv[16];
    for (int j = 0; j < 16; ++j) outv[j] = 0.f;
    for (int kt = 0; kt < 4; ++kt) {
        float wc[16];
#pragma unroll
        for (int kk = 0; kk < 16; ++kk) wc[kk] = Ws[kt * 16 + kk][c];
#pragma unroll
        for (int j = 0; j < 16; ++j)
#pragma unroll
            for (int kk = 0; kk < 16; ++kk)
                outv[j] += xs[n0 + j][kt * 16 + kk] * wc[kk];
    }
    unsigned short* tp = tT + ((long)b * 64 + c) * (long)NN + nb * 64 + n0;
#pragma unroll
    for (int j = 0; j < 16; j += 2)
        *(unsigned*)(tp + j) =
            (unsigned)f2bf(outv[j]) | ((unsigned)f2bf(outv[j + 1]) << 16);
}

__global__ __launch_bounds__(256) void h72_featbf(
    const unsigned short* __restrict__ xin, const float* __restrict__ W,
    unsigned short* __restrict__ tT)
{
    __shared__ float xs[64][68];
    __shared__ float Ws[64][68];
    const int tid = threadIdx.x;
    const int bid = blockIdx.x;
    const int b = bid >> 6, nb = bid & 63;
    {
        const int rr = tid >> 2, kq = (tid & 3) * 16;
        const unsigned short* xp = xin + ((long)b * NN + nb * 64 + rr) * 64 + kq;
        const float* wp = W + rr * 64 + kq;
        short8 v0 = *(const short8*)(xp);
        short8 v1 = *(const short8*)(xp + 8);
        for (int j = 0; j < 8; ++j) {
            xs[rr][kq + j]     = bf2f((unsigned short)v0[j]);
            xs[rr][kq + 8 + j] = bf2f((unsigned short)v1[j]);
        }
        for (int j = 0; j < 4; ++j)
            *(f32x4*)&Ws[rr][kq + j * 4] = *(const f32x4*)(wp + j * 4);
    }
    __syncthreads();
    const int c = tid >> 2, n0 = (tid & 3) * 16;
    float outv[16];
    for (int j = 0; j < 16; ++j) outv[j] = 0.f;
    for (int kt = 0; kt < 4; ++kt) {
        float wc[16];
#pragma unroll
        for (int kk = 0; kk < 16; ++kk) wc[kk] = Ws[kt * 16 + kk][c];
#pragma unroll
        for (int j = 0; j < 16; ++j)
#pragma unroll
            for (int kk = 0; kk < 16; ++kk)
                outv[j] += xs[n0 + j][kt * 16 + kk] * wc[kk];
    }
    unsigned short* tp = tT + ((long)b * 64 + c) * (long)NN + nb * 64 + n0;
#pragma unroll
    for (int j = 0; j < 16; j += 2)
        *(unsigned*)(tp + j) =
            (unsigned)f2bf(outv[j]) | ((unsigned)f2bf(outv[j + 1]) << 16);
}

// ---------------------------------------------------------------------------
// Final MLP: out = relu(concat(x1,x2,x3) @ Wl + bl) -> FLOAT32 output
// ---------------------------------------------------------------------------
__global__ __launch_bounds__(256) void h72_mlp(
    const unsigned short* __restrict__ x1, const unsigned short* __restrict__ x2,
    const unsigned short* __restrict__ x3, const float* __restrict__ Wl,
    const float* __restrict__ bl, float* __restrict__ out)
{
    __shared__ float hs[64][196];
    const int tid = threadIdx.x;
    const int bid = blockIdx.x;
    const int b = bid >> 6, nb = bid & 63;
    {
        const int rr = tid >> 2, kq = (tid & 3) * 16;
        const long base = ((long)b * NN + nb * 64 + rr) * 64 + kq;
        short8 u0 = *(const short8*)(x1 + base);
        short8 u1 = *(const short8*)(x1 + base + 8);
        short8 v0 = *(const short8*)(x2 + base);
        short8 v1 = *(const short8*)(x2 + base + 8);
        short8 w0 = *(const short8*)(x3 + base);
        short8 w1 = *(const short8*)(x3 + base + 8);
        for (int j = 0; j < 8; ++j) {
            hs[rr][  0 + kq + j]     = bf2f((unsigned short)u0[j]);
            hs[rr][  0 + kq + 8 + j] = bf2f((unsigned short)u1[j]);
            hs[rr][ 64 + kq + j]     = bf2f((unsigned short)v0[j]);
            hs[rr][ 64 + kq + 8 + j] = bf2f((unsigned short)v1[j]);
            hs[rr][128 + kq + j]     = bf2f((unsigned short)w0[j]);
            hs[rr][128 + kq + 8 + j] = bf2f((unsigned short)w1[j]);
        }
    }
    __syncthreads();
    const int c = tid >> 2, n0 = (tid & 3) * 16;
    float acc[16];
    const float blc = bl[c];
    for (int j = 0; j < 16; ++j) acc[j] = blc;
    for (int kt = 0; kt < 12; ++kt) {
        float wc[16];
#pragma unroll
        for (int kk = 0; kk < 16; ++kk) wc[kk] = Wl[(kt * 16 + kk) * 64 + c];
#pragma unroll
        for (int j = 0; j < 16; ++j)
#pragma unroll
            for (int kk = 0; kk < 16; ++kk)
                acc[j] += hs[n0 + j][kt * 16 + kk] * wc[kk];
    }
    float* op = out + ((long)b * NN + nb * 64 + n0) * 64 + c;
#pragma unroll
    for (int j = 0; j < 16; ++j) {
        float v2 = acc[j] > 0.f ? acc[j] : 0.f;
        op[j * 64] = v2;
    }
}

// ---------------------------------------------------------------------------
extern "C" void kernel_launch(void* const* d_in, const int* in_sizes, int n_in,
                              void* d_out, int out_size, void* d_ws, size_t ws_size,
                              hipStream_t stream)
{
    (void)in_sizes; (void)n_in; (void)out_size; (void)ws_size;
    const float* x   = (const float*)d_in[0];
    const float* adj = (const float*)d_in[1];
    const float* W1  = (const float*)d_in[2];
    const float* b1  = (const float*)d_in[3];
    const float* g1  = (const float*)d_in[4];
    const float* be1 = (const float*)d_in[5];
    const float* m1  = (const float*)d_in[6];
    const float* v1  = (const float*)d_in[7];
    const float* W2  = (const float*)d_in[8];
    const float* b2  = (const float*)d_in[9];
    const float* g2  = (const float*)d_in[10];
    const float* be2 = (const float*)d_in[11];
    const float* m2  = (const float*)d_in[12];
    const float* v2  = (const float*)d_in[13];
    const float* W3  = (const float*)d_in[14];
    const float* b3  = (const float*)d_in[15];
    const float* g3  = (const float*)d_in[16];
    const float* be3 = (const float*)d_in[17];
    const float* m3  = (const float*)d_in[18];
    const float* v3  = (const float*)d_in[19];
    const float* Wl  = (const float*)d_in[20];
    const float* bl  = (const float*)d_in[21];

    // OUTPUT IS FLOAT32: 1048576 floats = 4 MB. tT (bf16, 2 MB) lives in
    // d_out's second half; h72_mlp overwrites all of d_out last.
    float* out = (float*)d_out;
    unsigned short* tT = (unsigned short*)(out + 524288);

    char* ws = (char*)d_ws;
    unsigned short* x1 = (unsigned short*)(ws);
    unsigned short* x2 = (unsigned short*)(ws + 2097152);
    unsigned short* x3 = (unsigned short*)(ws + 4194304);

    h72_feat32<<<256, 256, 0, stream>>>(x, W1, tT);
    m72c_gcn<<<1024, 256, 0, stream>>>(adj, tT, b1, g1, be1, m1, v1, x1);

    h72_featbf<<<256, 256, 0, stream>>>(x1, W2, tT);
    m72c_gcn<<<1024, 256, 0, stream>>>(adj, tT, b2, g2, be2, m2, v2, x2);

    h72_featbf<<<256, 256, 0, stream>>>(x2, W3, tT);
    m72c_gcn<<<1024, 256, 0, stream>>>(adj, tT, b3, g3, be3, m3, v3, x3);

    h72_mlp<<<256, 256, 0, stream>>>(x1, x2, x3, Wl, bl, out);
}

// Round 20
// 338.649 us; speedup vs baseline: 1.3227x; 1.3227x over previous
//
#include <hip/hip_runtime.h>

typedef __attribute__((ext_vector_type(8))) short short8;
typedef __attribute__((ext_vector_type(4))) float f32x4;
typedef __attribute__((ext_vector_type(2))) unsigned u32x2;

#define NN 4096
#define BN_EPS 1e-3f

__device__ inline unsigned short f2bf(float f) {
    unsigned u = __builtin_bit_cast(unsigned, f);
    return (unsigned short)((u + 0x7fffu + ((u >> 16) & 1u)) >> 16);
}
__device__ inline float bf2f(unsigned short h) {
    return __builtin_bit_cast(float, ((unsigned)h) << 16);
}

// ---------------------------------------------------------------------------
// LDS-staged MFMA gcn, BARRIER-FREE hot loop. Ast slices are wave-private
// (each wave writes and reads only Ast[s]) so same-wave lgkmcnt ordering
// suffices — R19's __syncthreads() serialized stage vs consume block-wide
// and its 51 KB LDS cut occupancy to 3 blocks/CU (197 us). Chunk halved to
// 128 cols: LDS 35 KB -> 4 blocks/CU. Stage reads are 512 B contiguous per
// adj row (2 rows per instruction); MFMA B-fragments come from LDS.
// Block: 256 thr = 4 waves on the same 16 output rows, 4-way K-split.
// Fused LDS-reduce + bias/ReLU/BN epilogue (single cross-wave barrier).
// ---------------------------------------------------------------------------
__global__ __launch_bounds__(256) void m72d_gcn(
    const float* __restrict__ adj, const unsigned short* __restrict__ tT,
    const float* __restrict__ bias, const float* __restrict__ gamma,
    const float* __restrict__ beta, const float* __restrict__ mean,
    const float* __restrict__ var, unsigned short* __restrict__ xout)
{
    __shared__ unsigned short Ast[4][16][136];   // [wave][row][m'] bf16, pad 8
    __shared__ float red[4][16][68];
    const int tid = threadIdx.x;
    const int s = tid >> 6, lane = tid & 63;
    const int rl = lane & 15, grp = lane >> 4;
    const int bid = blockIdx.x;
    const int b = bid >> 8, rb = bid & 255;
    const int row16 = rb * 16;

    const float* abase = adj + ((long)b * NN + row16) * (long)NN;
    const unsigned short* t0 = tT + ((long)b * 64 + rl) * (long)NN;
    const unsigned short* t1 = t0 + 16 * (long)NN;
    const unsigned short* t2 = t0 + 32 * (long)NN;
    const unsigned short* t3 = t0 + 48 * (long)NN;
    const int m0 = s * 1024;
    const int srow = lane >> 5;          // stage: sub-row 0/1
    const int scol = (lane & 31) * 4;    // stage: col within 128-chunk

    f32x4 a0 = {}, a1 = {}, a2 = {}, a3 = {};

    for (int sc = 0; sc < 8; ++sc) {
        const int mb = m0 + sc * 128;
        // ---- stage: 16 rows x 128 fp32 -> bf16 LDS (wave-private slice).
        //      One instruction covers 2 rows x 512 B contiguous each. ----
#pragma unroll
        for (int r = 0; r < 16; r += 2) {
            const int row = r + srow;
            f32x4 v = *(const f32x4*)(abase + (long)row * NN + mb + scol);
            u32x2 p;
            p.x = (unsigned)f2bf(v.x) | ((unsigned)f2bf(v.y) << 16);
            p.y = (unsigned)f2bf(v.z) | ((unsigned)f2bf(v.w) << 16);
            *(u32x2*)&Ast[s][row][scol] = p;
        }
        // same-wave ds_write -> ds_read: compiler-inserted lgkmcnt orders it
        // ---- consume: 4 MFMA steps over the 128-col sub-chunk ----
#pragma unroll
        for (int it = 0; it < 4; ++it) {
            const int kk = it * 32 + grp * 8;     // k-slot offset incl. grp
            const int mA = mb + kk;
            short8 A0 = *(const short8*)(t0 + mA);
            short8 A1 = *(const short8*)(t1 + mA);
            short8 A2 = *(const short8*)(t2 + mA);
            short8 A3 = *(const short8*)(t3 + mA);
            short8 B = *(const short8*)&Ast[s][rl][kk];
            a0 = __builtin_amdgcn_mfma_f32_16x16x32_bf16(A0, B, a0, 0, 0, 0);
            a1 = __builtin_amdgcn_mfma_f32_16x16x32_bf16(A1, B, a1, 0, 0, 0);
            a2 = __builtin_amdgcn_mfma_f32_16x16x32_bf16(A2, B, a2, 0, 0, 0);
            a3 = __builtin_amdgcn_mfma_f32_16x16x32_bf16(A3, B, a3, 0, 0, 0);
        }
    }

    // D layout: col=rl -> node; row=grp*4+q -> feature within 16-group.
    *(f32x4*)&red[s][rl][ 0 + grp * 4] = a0;
    *(f32x4*)&red[s][rl][16 + grp * 4] = a1;
    *(f32x4*)&red[s][rl][32 + grp * 4] = a2;
    *(f32x4*)&red[s][rl][48 + grp * 4] = a3;
    __syncthreads();

    const int r2 = tid >> 4, cq = (tid & 15) * 4;
    f32x4 v = *(const f32x4*)&red[0][r2][cq];
    v += *(const f32x4*)&red[1][r2][cq];
    v += *(const f32x4*)&red[2][r2][cq];
    v += *(const f32x4*)&red[3][r2][cq];

    f32x4 bi = *(const f32x4*)(bias + cq);
    f32x4 mn = *(const f32x4*)(mean + cq);
    f32x4 vr = *(const f32x4*)(var + cq);
    f32x4 gm = *(const f32x4*)(gamma + cq);
    f32x4 bt = *(const f32x4*)(beta + cq);
    float o[4];
    for (int q = 0; q < 4; ++q) {
        float h = v[q] + bi[q];
        h = h > 0.f ? h : 0.f;
        o[q] = (h - mn[q]) * (gm[q] / sqrtf(vr[q] + BN_EPS)) + bt[q];
    }
    u32x2 o2;
    o2.x = (unsigned)f2bf(o[0]) | ((unsigned)f2bf(o[1]) << 16);
    o2.y = (unsigned)f2bf(o[2]) | ((unsigned)f2bf(o[3]) << 16);
    *(u32x2*)(xout + ((long)b * NN + row16 + r2) * 64 + cq) = o2;
}

// ---------------------------------------------------------------------------
// Feature transform: tT[b][c][n] = sum_k xin[b][n][k] * W[k][c]  (bf16 out)
// ---------------------------------------------------------------------------
__global__ __launch_bounds__(256) void h72_feat32(
    const float* __restrict__ xin, const float* __restrict__ W,
    unsigned short* __restrict__ tT)
{
    __shared__ float xs[64][68];
    __shared__ float Ws[64][68];
    const int tid = threadIdx.x;
    const int bid = blockIdx.x;
    const int b = bid >> 6, nb = bid & 63;
    {
        const int rr = tid >> 2, kq = (tid & 3) * 16;
        const float* xp = xin + ((long)b * NN + nb * 64 + rr) * 64 + kq;
        const float* wp = W + rr * 64 + kq;
        for (int j = 0; j < 4; ++j) {
            *(f32x4*)&xs[rr][kq + j * 4] = *(const f32x4*)(xp + j * 4);
            *(f32x4*)&Ws[rr][kq + j * 4] = *(const f32x4*)(wp + j * 4);
        }
    }
    __syncthreads();
    const int c = tid >> 2, n0 = (tid & 3) * 16;
    float outv[16];
    for (int j = 0; j < 16; ++j) outv[j] = 0.f;
    for (int kt = 0; kt < 4; ++kt) {
        float wc[16];
#pragma unroll
        for (int kk = 0; kk < 16; ++kk) wc[kk] = Ws[kt * 16 + kk][c];
#pragma unroll
        for (int j = 0; j < 16; ++j)
#pragma unroll
            for (int kk = 0; kk < 16; ++kk)
                outv[j] += xs[n0 + j][kt * 16 + kk] * wc[kk];
    }
    unsigned short* tp = tT + ((long)b * 64 + c) * (long)NN + nb * 64 + n0;
#pragma unroll
    for (int j = 0; j < 16; j += 2)
        *(unsigned*)(tp + j) =
            (unsigned)f2bf(outv[j]) | ((unsigned)f2bf(outv[j + 1]) << 16);
}

__global__ __launch_bounds__(256) void h72_featbf(
    const unsigned short* __restrict__ xin, const float* __restrict__ W,
    unsigned short* __restrict__ tT)
{
    __shared__ float xs[64][68];
    __shared__ float Ws[64][68];
    const int tid = threadIdx.x;
    const int bid = blockIdx.x;
    const int b = bid >> 6, nb = bid & 63;
    {
        const int rr = tid >> 2, kq = (tid & 3) * 16;
        const unsigned short* xp = xin + ((long)b * NN + nb * 64 + rr) * 64 + kq;
        const float* wp = W + rr * 64 + kq;
        short8 v0 = *(const short8*)(xp);
        short8 v1 = *(const short8*)(xp + 8);
        for (int j = 0; j < 8; ++j) {
            xs[rr][kq + j]     = bf2f((unsigned short)v0[j]);
            xs[rr][kq + 8 + j] = bf2f((unsigned short)v1[j]);
        }
        for (int j = 0; j < 4; ++j)
            *(f32x4*)&Ws[rr][kq + j * 4] = *(const f32x4*)(wp + j * 4);
    }
    __syncthreads();
    const int c = tid >> 2, n0 = (tid & 3) * 16;
    float outv[16];
    for (int j = 0; j < 16; ++j) outv[j] = 0.f;
    for (int kt = 0; kt < 4; ++kt) {
        float wc[16];
#pragma unroll
        for (int kk = 0; kk < 16; ++kk) wc[kk] = Ws[kt * 16 + kk][c];
#pragma unroll
        for (int j = 0; j < 16; ++j)
#pragma unroll
            for (int kk = 0; kk < 16; ++kk)
                outv[j] += xs[n0 + j][kt * 16 + kk] * wc[kk];
    }
    unsigned short* tp = tT + ((long)b * 64 + c) * (long)NN + nb * 64 + n0;
#pragma unroll
    for (int j = 0; j < 16; j += 2)
        *(unsigned*)(tp + j) =
            (unsigned)f2bf(outv[j]) | ((unsigned)f2bf(outv[j + 1]) << 16);
}

// ---------------------------------------------------------------------------
// Final MLP: out = relu(concat(x1,x2,x3) @ Wl + bl) -> FLOAT32 output
// ---------------------------------------------------------------------------
__global__ __launch_bounds__(256) void h72_mlp(
    const unsigned short* __restrict__ x1, const unsigned short* __restrict__ x2,
    const unsigned short* __restrict__ x3, const float* __restrict__ Wl,
    const float* __restrict__ bl, float* __restrict__ out)
{
    __shared__ float hs[64][196];
    const int tid = threadIdx.x;
    const int bid = blockIdx.x;
    const int b = bid >> 6, nb = bid & 63;
    {
        const int rr = tid >> 2, kq = (tid & 3) * 16;
        const long base = ((long)b * NN + nb * 64 + rr) * 64 + kq;
        short8 u0 = *(const short8*)(x1 + base);
        short8 u1 = *(const short8*)(x1 + base + 8);
        short8 v0 = *(const short8*)(x2 + base);
        short8 v1 = *(const short8*)(x2 + base + 8);
        short8 w0 = *(const short8*)(x3 + base);
        short8 w1 = *(const short8*)(x3 + base + 8);
        for (int j = 0; j < 8; ++j) {
            hs[rr][  0 + kq + j]     = bf2f((unsigned short)u0[j]);
            hs[rr][  0 + kq + 8 + j] = bf2f((unsigned short)u1[j]);
            hs[rr][ 64 + kq + j]     = bf2f((unsigned short)v0[j]);
            hs[rr][ 64 + kq + 8 + j] = bf2f((unsigned short)v1[j]);
            hs[rr][128 + kq + j]     = bf2f((unsigned short)w0[j]);
            hs[rr][128 + kq + 8 + j] = bf2f((unsigned short)w1[j]);
        }
    }
    __syncthreads();
    const int c = tid >> 2, n0 = (tid & 3) * 16;
    float acc[16];
    const float blc = bl[c];
    for (int j = 0; j < 16; ++j) acc[j] = blc;
    for (int kt = 0; kt < 12; ++kt) {
        float wc[16];
#pragma unroll
        for (int kk = 0; kk < 16; ++kk) wc[kk] = Wl[(kt * 16 + kk) * 64 + c];
#pragma unroll
        for (int j = 0; j < 16; ++j)
#pragma unroll
            for (int kk = 0; kk < 16; ++kk)
                acc[j] += hs[n0 + j][kt * 16 + kk] * wc[kk];
    }
    float* op = out + ((long)b * NN + nb * 64 + n0) * 64 + c;
#pragma unroll
    for (int j = 0; j < 16; ++j) {
        float v2 = acc[j] > 0.f ? acc[j] : 0.f;
        op[j * 64] = v2;
    }
}

// ---------------------------------------------------------------------------
extern "C" void kernel_launch(void* const* d_in, const int* in_sizes, int n_in,
                              void* d_out, int out_size, void* d_ws, size_t ws_size,
                              hipStream_t stream)
{
    (void)in_sizes; (void)n_in; (void)out_size; (void)ws_size;
    const float* x   = (const float*)d_in[0];
    const float* adj = (const float*)d_in[1];
    const float* W1  = (const float*)d_in[2];
    const float* b1  = (const float*)d_in[3];
    const float* g1  = (const float*)d_in[4];
    const float* be1 = (const float*)d_in[5];
    const float* m1  = (const float*)d_in[6];
    const float* v1  = (const float*)d_in[7];
    const float* W2  = (const float*)d_in[8];
    const float* b2  = (const float*)d_in[9];
    const float* g2  = (const float*)d_in[10];
    const float* be2 = (const float*)d_in[11];
    const float* m2  = (const float*)d_in[12];
    const float* v2  = (const float*)d_in[13];
    const float* W3  = (const float*)d_in[14];
    const float* b3  = (const float*)d_in[15];
    const float* g3  = (const float*)d_in[16];
    const float* be3 = (const float*)d_in[17];
    const float* m3  = (const float*)d_in[18];
    const float* v3  = (const float*)d_in[19];
    const float* Wl  = (const float*)d_in[20];
    const float* bl  = (const float*)d_in[21];

    // OUTPUT IS FLOAT32: 1048576 floats = 4 MB. tT (bf16, 2 MB) lives in
    // d_out's second half; h72_mlp overwrites all of d_out last.
    float* out = (float*)d_out;
    unsigned short* tT = (unsigned short*)(out + 524288);

    char* ws = (char*)d_ws;
    unsigned short* x1 = (unsigned short*)(ws);
    unsigned short* x2 = (unsigned short*)(ws + 2097152);
    unsigned short* x3 = (unsigned short*)(ws + 4194304);

    h72_feat32<<<256, 256, 0, stream>>>(x, W1, tT);
    m72d_gcn<<<1024, 256, 0, stream>>>(adj, tT, b1, g1, be1, m1, v1, x1);

    h72_featbf<<<256, 256, 0, stream>>>(x1, W2, tT);
    m72d_gcn<<<1024, 256, 0, stream>>>(adj, tT, b2, g2, be2, m2, v2, x2);

    h72_featbf<<<256, 256, 0, stream>>>(x2, W3, tT);
    m72d_gcn<<<1024, 256, 0, stream>>>(adj, tT, b3, g3, be3, m3, v3, x3);

    h72_mlp<<<256, 256, 0, stream>>>(x1, x2, x3, Wl, bl, out);
}

// Round 21
// 268.664 us; speedup vs baseline: 1.6673x; 1.2605x over previous
//
#include <hip/hip_runtime.h>

typedef __attribute__((ext_vector_type(8))) short short8;
typedef __attribute__((ext_vector_type(4))) float f32x4;
typedef __attribute__((ext_vector_type(2))) unsigned u32x2;

#define NN 4096
#define BN_EPS 1e-3f

__device__ inline unsigned short f2bf(float f) {
    unsigned u = __builtin_bit_cast(unsigned, f);
    return (unsigned short)((u + 0x7fffu + ((u >> 16) & 1u)) >> 16);
}
__device__ inline float bf2f(unsigned short h) {
    return __builtin_bit_cast(float, ((unsigned)h) << 16);
}
__device__ inline short8 pk8(f32x4 f0, f32x4 f1) {
    short8 B;
    B[0] = (short)f2bf(f0.x); B[1] = (short)f2bf(f0.y);
    B[2] = (short)f2bf(f0.z); B[3] = (short)f2bf(f0.w);
    B[4] = (short)f2bf(f1.x); B[5] = (short)f2bf(f1.y);
    B[6] = (short)f2bf(f1.z); B[7] = (short)f2bf(f1.w);
    return B;
}

// ---------------------------------------------------------------------------
// MFMA gcn with 2 row-groups per block (A-operand reuse). The tT A-fragment
// gather was 2/3 of all VMEM requests in every prior variant (the pinned
// ~100 us invariant); loading A once per MFMA window and feeding TWO adj
// row-groups halves the A-request share and doubles per-wave memory ILP.
// Block: 256 thr = 4 waves K-split, 32 output rows (2 rgs x 16).
// Direct global loads (R14-proven pattern); LDS reduce + fused BN epilogue.
// ---------------------------------------------------------------------------
__global__ __launch_bounds__(256) void n72_gcn(
    const float* __restrict__ adj, const unsigned short* __restrict__ tT,
    const float* __restrict__ bias, const float* __restrict__ gamma,
    const float* __restrict__ beta, const float* __restrict__ mean,
    const float* __restrict__ var, unsigned short* __restrict__ xout)
{
    const int tid = threadIdx.x;
    const int s = tid >> 6, lane = tid & 63;
    const int rl = lane & 15, grp = lane >> 4;
    const int bid = blockIdx.x;
    const int b = bid >> 7, rb = bid & 127;
    const int row32 = rb * 32;

    const float* arow0 = adj + ((long)b * NN + row32 + rl) * (long)NN;
    const float* arow1 = arow0 + 16 * (long)NN;
    const unsigned short* t0 = tT + ((long)b * 64 + rl) * (long)NN;
    const unsigned short* t1 = t0 + 16 * (long)NN;
    const unsigned short* t2 = t0 + 32 * (long)NN;
    const unsigned short* t3 = t0 + 48 * (long)NN;
    const int m0 = s * 1024 + grp * 8;

    f32x4 p0 = {}, p1 = {}, p2 = {}, p3 = {};   // rg0 acc
    f32x4 q0 = {}, q1 = {}, q2 = {}, q3 = {};   // rg1 acc

    for (int it = 0; it < 32; ++it) {
        const int m = m0 + it * 32;
        short8 A0 = *(const short8*)(t0 + m);
        short8 A1 = *(const short8*)(t1 + m);
        short8 A2 = *(const short8*)(t2 + m);
        short8 A3 = *(const short8*)(t3 + m);
        f32x4 f0 = *(const f32x4*)(arow0 + m);
        f32x4 f1 = *(const f32x4*)(arow0 + m + 4);
        f32x4 g0 = *(const f32x4*)(arow1 + m);
        f32x4 g1 = *(const f32x4*)(arow1 + m + 4);
        short8 B0 = pk8(f0, f1);
        short8 B1 = pk8(g0, g1);
        p0 = __builtin_amdgcn_mfma_f32_16x16x32_bf16(A0, B0, p0, 0, 0, 0);
        p1 = __builtin_amdgcn_mfma_f32_16x16x32_bf16(A1, B0, p1, 0, 0, 0);
        p2 = __builtin_amdgcn_mfma_f32_16x16x32_bf16(A2, B0, p2, 0, 0, 0);
        p3 = __builtin_amdgcn_mfma_f32_16x16x32_bf16(A3, B0, p3, 0, 0, 0);
        q0 = __builtin_amdgcn_mfma_f32_16x16x32_bf16(A0, B1, q0, 0, 0, 0);
        q1 = __builtin_amdgcn_mfma_f32_16x16x32_bf16(A1, B1, q1, 0, 0, 0);
        q2 = __builtin_amdgcn_mfma_f32_16x16x32_bf16(A2, B1, q2, 0, 0, 0);
        q3 = __builtin_amdgcn_mfma_f32_16x16x32_bf16(A3, B1, q3, 0, 0, 0);
    }

    // D layout: col=rl -> node (within rg); row=grp*4+q -> feature in 16-grp.
    __shared__ float red[4][2][16][68];
    *(f32x4*)&red[s][0][rl][ 0 + grp * 4] = p0;
    *(f32x4*)&red[s][0][rl][16 + grp * 4] = p1;
    *(f32x4*)&red[s][0][rl][32 + grp * 4] = p2;
    *(f32x4*)&red[s][0][rl][48 + grp * 4] = p3;
    *(f32x4*)&red[s][1][rl][ 0 + grp * 4] = q0;
    *(f32x4*)&red[s][1][rl][16 + grp * 4] = q1;
    *(f32x4*)&red[s][1][rl][32 + grp * 4] = q2;
    *(f32x4*)&red[s][1][rl][48 + grp * 4] = q3;
    __syncthreads();

    const int r2 = tid >> 4, cq = (tid & 15) * 4;
    f32x4 bi = *(const f32x4*)(bias + cq);
    f32x4 mn = *(const f32x4*)(mean + cq);
    f32x4 vr = *(const f32x4*)(var + cq);
    f32x4 gm = *(const f32x4*)(gamma + cq);
    f32x4 bt = *(const f32x4*)(beta + cq);
    f32x4 sc;
    for (int q = 0; q < 4; ++q) sc[q] = gm[q] / sqrtf(vr[q] + BN_EPS);

    for (int rg = 0; rg < 2; ++rg) {
        f32x4 v = *(const f32x4*)&red[0][rg][r2][cq];
        v += *(const f32x4*)&red[1][rg][r2][cq];
        v += *(const f32x4*)&red[2][rg][r2][cq];
        v += *(const f32x4*)&red[3][rg][r2][cq];
        float o[4];
        for (int q = 0; q < 4; ++q) {
            float h = v[q] + bi[q];
            h = h > 0.f ? h : 0.f;
            o[q] = (h - mn[q]) * sc[q] + bt[q];
        }
        u32x2 o2;
        o2.x = (unsigned)f2bf(o[0]) | ((unsigned)f2bf(o[1]) << 16);
        o2.y = (unsigned)f2bf(o[2]) | ((unsigned)f2bf(o[3]) << 16);
        *(u32x2*)(xout + ((long)b * NN + row32 + rg * 16 + r2) * 64 + cq) = o2;
    }
}

// ---------------------------------------------------------------------------
// Feature transform: tT[b][c][n] = sum_k xin[b][n][k] * W[k][c]  (bf16 out)
// ---------------------------------------------------------------------------
__global__ __launch_bounds__(256) void h72_feat32(
    const float* __restrict__ xin, const float* __restrict__ W,
    unsigned short* __restrict__ tT)
{
    __shared__ float xs[64][68];
    __shared__ float Ws[64][68];
    const int tid = threadIdx.x;
    const int bid = blockIdx.x;
    const int b = bid >> 6, nb = bid & 63;
    {
        const int rr = tid >> 2, kq = (tid & 3) * 16;
        const float* xp = xin + ((long)b * NN + nb * 64 + rr) * 64 + kq;
        const float* wp = W + rr * 64 + kq;
        for (int j = 0; j < 4; ++j) {
            *(f32x4*)&xs[rr][kq + j * 4] = *(const f32x4*)(xp + j * 4);
            *(f32x4*)&Ws[rr][kq + j * 4] = *(const f32x4*)(wp + j * 4);
        }
    }
    __syncthreads();
    const int c = tid >> 2, n0 = (tid & 3) * 16;
    float outv[16];
    for (int j = 0; j < 16; ++j) outv[j] = 0.f;
    for (int kt = 0; kt < 4; ++kt) {
        float wc[16];
#pragma unroll
        for (int kk = 0; kk < 16; ++kk) wc[kk] = Ws[kt * 16 + kk][c];
#pragma unroll
        for (int j = 0; j < 16; ++j)
#pragma unroll
            for (int kk = 0; kk < 16; ++kk)
                outv[j] += xs[n0 + j][kt * 16 + kk] * wc[kk];
    }
    unsigned short* tp = tT + ((long)b * 64 + c) * (long)NN + nb * 64 + n0;
#pragma unroll
    for (int j = 0; j < 16; j += 2)
        *(unsigned*)(tp + j) =
            (unsigned)f2bf(outv[j]) | ((unsigned)f2bf(outv[j + 1]) << 16);
}

__global__ __launch_bounds__(256) void h72_featbf(
    const unsigned short* __restrict__ xin, const float* __restrict__ W,
    unsigned short* __restrict__ tT)
{
    __shared__ float xs[64][68];
    __shared__ float Ws[64][68];
    const int tid = threadIdx.x;
    const int bid = blockIdx.x;
    const int b = bid >> 6, nb = bid & 63;
    {
        const int rr = tid >> 2, kq = (tid & 3) * 16;
        const unsigned short* xp = xin + ((long)b * NN + nb * 64 + rr) * 64 + kq;
        const float* wp = W + rr * 64 + kq;
        short8 v0 = *(const short8*)(xp);
        short8 v1 = *(const short8*)(xp + 8);
        for (int j = 0; j < 8; ++j) {
            xs[rr][kq + j]     = bf2f((unsigned short)v0[j]);
            xs[rr][kq + 8 + j] = bf2f((unsigned short)v1[j]);
        }
        for (int j = 0; j < 4; ++j)
            *(f32x4*)&Ws[rr][kq + j * 4] = *(const f32x4*)(wp + j * 4);
    }
    __syncthreads();
    const int c = tid >> 2, n0 = (tid & 3) * 16;
    float outv[16];
    for (int j = 0; j < 16; ++j) outv[j] = 0.f;
    for (int kt = 0; kt < 4; ++kt) {
        float wc[16];
#pragma unroll
        for (int kk = 0; kk < 16; ++kk) wc[kk] = Ws[kt * 16 + kk][c];
#pragma unroll
        for (int j = 0; j < 16; ++j)
#pragma unroll
            for (int kk = 0; kk < 16; ++kk)
                outv[j] += xs[n0 + j][kt * 16 + kk] * wc[kk];
    }
    unsigned short* tp = tT + ((long)b * 64 + c) * (long)NN + nb * 64 + n0;
#pragma unroll
    for (int j = 0; j < 16; j += 2)
        *(unsigned*)(tp + j) =
            (unsigned)f2bf(outv[j]) | ((unsigned)f2bf(outv[j + 1]) << 16);
}

// ---------------------------------------------------------------------------
// Final MLP: out = relu(concat(x1,x2,x3) @ Wl + bl) -> FLOAT32 output
// ---------------------------------------------------------------------------
__global__ __launch_bounds__(256) void h72_mlp(
    const unsigned short* __restrict__ x1, const unsigned short* __restrict__ x2,
    const unsigned short* __restrict__ x3, const float* __restrict__ Wl,
    const float* __restrict__ bl, float* __restrict__ out)
{
    __shared__ float hs[64][196];
    const int tid = threadIdx.x;
    const int bid = blockIdx.x;
    const int b = bid >> 6, nb = bid & 63;
    {
        const int rr = tid >> 2, kq = (tid & 3) * 16;
        const long base = ((long)b * NN + nb * 64 + rr) * 64 + kq;
        short8 u0 = *(const short8*)(x1 + base);
        short8 u1 = *(const short8*)(x1 + base + 8);
        short8 v0 = *(const short8*)(x2 + base);
        short8 v1 = *(const short8*)(x2 + base + 8);
        short8 w0 = *(const short8*)(x3 + base);
        short8 w1 = *(const short8*)(x3 + base + 8);
        for (int j = 0; j < 8; ++j) {
            hs[rr][  0 + kq + j]     = bf2f((unsigned short)u0[j]);
            hs[rr][  0 + kq + 8 + j] = bf2f((unsigned short)u1[j]);
            hs[rr][ 64 + kq + j]     = bf2f((unsigned short)v0[j]);
            hs[rr][ 64 + kq + 8 + j] = bf2f((unsigned short)v1[j]);
            hs[rr][128 + kq + j]     = bf2f((unsigned short)w0[j]);
            hs[rr][128 + kq + 8 + j] = bf2f((unsigned short)w1[j]);
        }
    }
    __syncthreads();
    const int c = tid >> 2, n0 = (tid & 3) * 16;
    float acc[16];
    const float blc = bl[c];
    for (int j = 0; j < 16; ++j) acc[j] = blc;
    for (int kt = 0; kt < 12; ++kt) {
        float wc[16];
#pragma unroll
        for (int kk = 0; kk < 16; ++kk) wc[kk] = Wl[(kt * 16 + kk) * 64 + c];
#pragma unroll
        for (int j = 0; j < 16; ++j)
#pragma unroll
            for (int kk = 0; kk < 16; ++kk)
                acc[j] += hs[n0 + j][kt * 16 + kk] * wc[kk];
    }
    float* op = out + ((long)b * NN + nb * 64 + n0) * 64 + c;
#pragma unroll
    for (int j = 0; j < 16; ++j) {
        float v2 = acc[j] > 0.f ? acc[j] : 0.f;
        op[j * 64] = v2;
    }
}

// ---------------------------------------------------------------------------
extern "C" void kernel_launch(void* const* d_in, const int* in_sizes, int n_in,
                              void* d_out, int out_size, void* d_ws, size_t ws_size,
                              hipStream_t stream)
{
    (void)in_sizes; (void)n_in; (void)out_size; (void)ws_size;
    const float* x   = (const float*)d_in[0];
    const float* adj = (const float*)d_in[1];
    const float* W1  = (const float*)d_in[2];
    const float* b1  = (const float*)d_in[3];
    const float* g1  = (const float*)d_in[4];
    const float* be1 = (const float*)d_in[5];
    const float* m1  = (const float*)d_in[6];
    const float* v1  = (const float*)d_in[7];
    const float* W2  = (const float*)d_in[8];
    const float* b2  = (const float*)d_in[9];
    const float* g2  = (const float*)d_in[10];
    const float* be2 = (const float*)d_in[11];
    const float* m2  = (const float*)d_in[12];
    const float* v2  = (const float*)d_in[13];
    const float* W3  = (const float*)d_in[14];
    const float* b3  = (const float*)d_in[15];
    const float* g3  = (const float*)d_in[16];
    const float* be3 = (const float*)d_in[17];
    const float* m3  = (const float*)d_in[18];
    const float* v3  = (const float*)d_in[19];
    const float* Wl  = (const float*)d_in[20];
    const float* bl  = (const float*)d_in[21];

    // OUTPUT IS FLOAT32: 1048576 floats = 4 MB. tT (bf16, 2 MB) lives in
    // d_out's second half; h72_mlp overwrites all of d_out last.
    float* out = (float*)d_out;
    unsigned short* tT = (unsigned short*)(out + 524288);

    char* ws = (char*)d_ws;
    unsigned short* x1 = (unsigned short*)(ws);
    unsigned short* x2 = (unsigned short*)(ws + 2097152);
    unsigned short* x3 = (unsigned short*)(ws + 4194304);

    h72_feat32<<<256, 256, 0, stream>>>(x, W1, tT);
    n72_gcn<<<512, 256, 0, stream>>>(adj, tT, b1, g1, be1, m1, v1, x1);

    h72_featbf<<<256, 256, 0, stream>>>(x1, W2, tT);
    n72_gcn<<<512, 256, 0, stream>>>(adj, tT, b2, g2, be2, m2, v2, x2);

    h72_featbf<<<256, 256, 0, stream>>>(x2, W3, tT);
    n72_gcn<<<512, 256, 0, stream>>>(adj, tT, b3, g3, be3, m3, v3, x3);

    h72_mlp<<<256, 256, 0, stream>>>(x1, x2, x3, Wl, bl, out);
}